// Round 8
// baseline (223.285 us; speedup 1.0000x reference)
//
#include <hip/hip_runtime.h>
#include <hip/hip_bf16.h>
#include <cstdint>

// Problem constants
#define BATCH   4
#define SEQ     1024
#define DM      512
#define NH      8
#define DH      64
#define RH      64

typedef float f32x4 __attribute__((ext_vector_type(4)));
typedef __bf16 bf16x8 __attribute__((ext_vector_type(8)));

// workspace byte offsets (ws is 256 MiB)
#define QB_OFF    (0)               // bf16 [B][NH][S][DH]   4 MB
#define KB_OFF    (4  << 20)        // bf16 [B][NH][S][DH]   4 MB
#define VT_OFF    (8  << 20)        // bf16 [B][NH][DH][S]   4 MB
#define XB_OFF    (12 << 20)        // bf16 [B*S][DM]        4 MB
#define WT_OFF    (16 << 20)        // bf16 [1536][512] (n,k) 1.5 MB
#define WOT_OFF   (18 << 20)        // bf16 [512][512]  (n,k) 0.5 MB
#define W2T_OFF   (19 << 20)        // bf16 [16][64] (h,k), rows 8..15 = 0
#define AW_OFF    (20 << 20)        // f32  [B*S][RH]        1 MB
#define CW_OFF    (21 << 20)        // f32  [B*S][RH]        1 MB
#define CTXB_OFF  (22 << 20)        // bf16 [B*S][DM]        4 MB
#define BIAS_OFF  (32 << 20)        // bf16 [B][NH][S][S]   64 MB

// ---------------------------------------------------------------------------
// cast x (f32 -> bf16)
// ---------------------------------------------------------------------------
__global__ __launch_bounds__(256) void cast_x(
    const float* __restrict__ x, __bf16* __restrict__ xb)
{
    const size_t i = ((size_t)blockIdx.x * 256 + threadIdx.x) * 8;
    const float4 a = *(const float4*)&x[i];
    const float4 b = *(const float4*)&x[i + 4];
    bf16x8 o;
    o[0] = (__bf16)a.x; o[1] = (__bf16)a.y; o[2] = (__bf16)a.z; o[3] = (__bf16)a.w;
    o[4] = (__bf16)b.x; o[5] = (__bf16)b.y; o[6] = (__bf16)b.z; o[7] = (__bf16)b.w;
    *(bf16x8*)&xb[i] = o;
}

// ---------------------------------------------------------------------------
// cast + transpose weights: W[k][n] f32 -> Wt[n][k] bf16.
// ---------------------------------------------------------------------------
__global__ __launch_bounds__(256) void cast_w(
    const float* __restrict__ Wq, const float* __restrict__ Wk,
    const float* __restrict__ Wv, const float* __restrict__ Wo,
    __bf16* __restrict__ Wt, __bf16* __restrict__ Wot)
{
    const int t = threadIdx.x;
    const int k0 = blockIdx.x * 64;
    const int n0 = blockIdx.y * 64;
    const int z  = blockIdx.z;
    const float* __restrict__ src = (z == 0) ? Wq : (z == 1) ? Wk : (z == 2) ? Wv : Wo;
    __bf16* __restrict__ dst = (z < 3) ? (Wt + (size_t)(z * 512 + n0) * 512)
                                       : (Wot + (size_t)n0 * 512);

    __shared__ __align__(16) float Ts[64][65];
    #pragma unroll
    for (int i = 0; i < 4; ++i) {
        const int id = t + i * 256;           // 0..1023
        const int row = id >> 4, c4 = (id & 15) * 4;
        const float4 v = *(const float4*)&src[(size_t)(k0 + row) * DM + n0 + c4];
        Ts[row][c4 + 0] = v.x; Ts[row][c4 + 1] = v.y;
        Ts[row][c4 + 2] = v.z; Ts[row][c4 + 3] = v.w;
    }
    __syncthreads();
    #pragma unroll
    for (int i = 0; i < 2; ++i) {
        const int id = t + i * 256;           // 0..511
        const int rn = id >> 3, ck = (id & 7) * 8;
        bf16x8 o;
        #pragma unroll
        for (int j = 0; j < 8; ++j) o[j] = (__bf16)Ts[ck + j][rn];
        *(bf16x8*)&dst[(size_t)rn * 512 + k0 + ck] = o;
    }
}

// ---------------------------------------------------------------------------
// MFMA GEMM (QKV). XCD-swizzled grid (384 blocks).
// ---------------------------------------------------------------------------
__global__ __launch_bounds__(256) void gemm_qkv_mfma(
    const __bf16* __restrict__ xb, const __bf16* __restrict__ Wt,
    const float* __restrict__ bq, const float* __restrict__ bk,
    const float* __restrict__ bv,
    __bf16* __restrict__ Qb, __bf16* __restrict__ Kb, __bf16* __restrict__ Vtb)
{
    const int t = threadIdx.x;
    const int wave = t >> 6, lane = t & 63;
    const int wm = wave >> 1, wn = wave & 1;
    const int r = lane & 15, kc = lane >> 4, q4 = kc * 4;
    const int lin = blockIdx.y * 12 + blockIdx.x;            // 0..383
    const int swz = (lin & 7) * 48 + (lin >> 3);             // XCD-contiguous
    const int m0 = (swz / 12) * 128;
    const int n0 = (swz % 12) * 128;          // 0..1535
    const int sec = n0 >> 9;                  // 0=Q 1=K 2=V
    const int nn = n0 & 511;

    __shared__ __align__(16) char smem[36864];
    __bf16* __restrict__ As = (__bf16*)smem;            // [128][72]
    __bf16* __restrict__ Bs = (__bf16*)(smem + 18432);  // [128][72]

    f32x4 acc[4][4];
    #pragma unroll
    for (int i = 0; i < 4; ++i)
        #pragma unroll
        for (int j = 0; j < 4; ++j) acc[i][j] = {0.f, 0.f, 0.f, 0.f};

    const int srow = t >> 3, sck = (t & 7) * 8;
    const __bf16* __restrict__ Ag = xb + (size_t)(m0 + srow) * 512 + sck;
    const __bf16* __restrict__ Bg = Wt + (size_t)(n0 + srow) * 512 + sck;

    for (int k0 = 0; k0 < 512; k0 += 64) {
        bf16x8 ra[4], rb[4];
        #pragma unroll
        for (int i = 0; i < 4; ++i) {
            ra[i] = *(const bf16x8*)(Ag + (size_t)i * 32 * 512 + k0);
            rb[i] = *(const bf16x8*)(Bg + (size_t)i * 32 * 512 + k0);
        }
        __syncthreads();
        #pragma unroll
        for (int i = 0; i < 4; ++i) {
            *(bf16x8*)&As[(srow + i * 32) * 72 + sck] = ra[i];
            *(bf16x8*)&Bs[(srow + i * 32) * 72 + sck] = rb[i];
        }
        __syncthreads();
        #pragma unroll
        for (int ks = 0; ks < 2; ++ks) {
            bf16x8 af[4], bf[4];
            #pragma unroll
            for (int mf = 0; mf < 4; ++mf)
                af[mf] = *(const bf16x8*)&As[(wm * 64 + mf * 16 + r) * 72 + ks * 32 + kc * 8];
            #pragma unroll
            for (int nf = 0; nf < 4; ++nf)
                bf[nf] = *(const bf16x8*)&Bs[(wn * 64 + nf * 16 + r) * 72 + ks * 32 + kc * 8];
            #pragma unroll
            for (int mf = 0; mf < 4; ++mf)
                #pragma unroll
                for (int nf = 0; nf < 4; ++nf)
                    acc[mf][nf] = __builtin_amdgcn_mfma_f32_16x16x32_bf16(
                        af[mf], bf[nf], acc[mf][nf], 0, 0, 0);
        }
    }

    const float* __restrict__ bias = (sec == 0) ? bq : (sec == 1) ? bk : bv;
    __syncthreads();
    __bf16* __restrict__ Ls = (__bf16*)smem;            // [128][136]
    if (sec < 2) {
        #pragma unroll
        for (int mf = 0; mf < 4; ++mf)
            #pragma unroll
            for (int nf = 0; nf < 4; ++nf) {
                const int n_l = wn * 64 + nf * 16 + r;
                const float bb = bias[nn + n_l];
                #pragma unroll
                for (int rr = 0; rr < 4; ++rr)
                    Ls[(wm * 64 + mf * 16 + q4 + rr) * 136 + n_l] =
                        (__bf16)(acc[mf][nf][rr] + bb);
            }
    } else {
        #pragma unroll
        for (int mf = 0; mf < 4; ++mf)
            #pragma unroll
            for (int nf = 0; nf < 4; ++nf) {
                const int n_l = wn * 64 + nf * 16 + r;
                const float bb = bias[nn + n_l];
                #pragma unroll
                for (int rr = 0; rr < 4; ++rr)
                    Ls[n_l * 136 + (wm * 64 + mf * 16 + q4 + rr)] =
                        (__bf16)(acc[mf][nf][rr] + bb);
            }
    }
    __syncthreads();

    const int b = m0 >> 10, sbase = m0 & 1023;
    if (sec < 2) {
        __bf16* __restrict__ dst = sec ? Kb : Qb;
        #pragma unroll
        for (int i = 0; i < 8; ++i) {
            const int id = t + i * 256;
            const int row = id >> 4, nc = (id & 15) * 8;
            const bf16x8 v = *(const bf16x8*)&Ls[row * 136 + nc];
            const int ng = nn + nc, h = ng >> 6, c = ng & 63;
            *(bf16x8*)&dst[((size_t)(b * NH + h) * SEQ + sbase + row) * DH + c] = v;
        }
    } else {
        #pragma unroll
        for (int i = 0; i < 8; ++i) {
            const int id = t + i * 256;
            const int nrow = id >> 4, mc = (id & 15) * 8;
            const bf16x8 v = *(const bf16x8*)&Ls[nrow * 136 + mc];
            const int ng = nn + nrow, h = ng >> 6, c = ng & 63;
            *(bf16x8*)&Vtb[((size_t)(b * NH + h) * DH + c) * SEQ + sbase + mc] = v;
        }
    }
}

// ---------------------------------------------------------------------------
// MFMA GEMM (out). XCD-swizzled grid (128 blocks).
// ---------------------------------------------------------------------------
__global__ __launch_bounds__(256) void gemm_out_mfma(
    const __bf16* __restrict__ ctxb, const __bf16* __restrict__ Wot,
    const float* __restrict__ bo, float* __restrict__ out)
{
    const int t = threadIdx.x;
    const int wave = t >> 6, lane = t & 63;
    const int wm = wave >> 1, wn = wave & 1;
    const int r = lane & 15, kc = lane >> 4, q4 = kc * 4;
    const int lin = blockIdx.y * 4 + blockIdx.x;             // 0..127
    const int swz = (lin & 7) * 16 + (lin >> 3);
    const int m0 = (swz / 4) * 128;
    const int n0 = (swz % 4) * 128;

    __shared__ __align__(16) char smem[36864];
    __bf16* __restrict__ As = (__bf16*)smem;
    __bf16* __restrict__ Bs = (__bf16*)(smem + 18432);

    f32x4 acc[4][4];
    #pragma unroll
    for (int i = 0; i < 4; ++i)
        #pragma unroll
        for (int j = 0; j < 4; ++j) acc[i][j] = {0.f, 0.f, 0.f, 0.f};

    const int srow = t >> 3, sck = (t & 7) * 8;
    const __bf16* __restrict__ Ag = ctxb + (size_t)(m0 + srow) * 512 + sck;
    const __bf16* __restrict__ Bg = Wot + (size_t)(n0 + srow) * 512 + sck;

    for (int k0 = 0; k0 < 512; k0 += 64) {
        bf16x8 ra[4], rb[4];
        #pragma unroll
        for (int i = 0; i < 4; ++i) {
            ra[i] = *(const bf16x8*)(Ag + (size_t)i * 32 * 512 + k0);
            rb[i] = *(const bf16x8*)(Bg + (size_t)i * 32 * 512 + k0);
        }
        __syncthreads();
        #pragma unroll
        for (int i = 0; i < 4; ++i) {
            *(bf16x8*)&As[(srow + i * 32) * 72 + sck] = ra[i];
            *(bf16x8*)&Bs[(srow + i * 32) * 72 + sck] = rb[i];
        }
        __syncthreads();
        #pragma unroll
        for (int ks = 0; ks < 2; ++ks) {
            bf16x8 af[4], bf[4];
            #pragma unroll
            for (int mf = 0; mf < 4; ++mf)
                af[mf] = *(const bf16x8*)&As[(wm * 64 + mf * 16 + r) * 72 + ks * 32 + kc * 8];
            #pragma unroll
            for (int nf = 0; nf < 4; ++nf)
                bf[nf] = *(const bf16x8*)&Bs[(wn * 64 + nf * 16 + r) * 72 + ks * 32 + kc * 8];
            #pragma unroll
            for (int mf = 0; mf < 4; ++mf)
                #pragma unroll
                for (int nf = 0; nf < 4; ++nf)
                    acc[mf][nf] = __builtin_amdgcn_mfma_f32_16x16x32_bf16(
                        af[mf], bf[nf], acc[mf][nf], 0, 0, 0);
        }
    }

    #pragma unroll
    for (int mf = 0; mf < 4; ++mf)
        #pragma unroll
        for (int nf = 0; nf < 4; ++nf) {
            const int n_l = wn * 64 + nf * 16 + r;
            const float bb = bo[n0 + n_l];
            #pragma unroll
            for (int rr = 0; rr < 4; ++rr)
                out[(size_t)(m0 + wm * 64 + mf * 16 + q4 + rr) * DM + n0 + n_l] =
                    acc[mf][nf][rr] + bb;
        }
}

// ---------------------------------------------------------------------------
// Relative-feature precompute + W2t emit (blocks 0..15)
// ---------------------------------------------------------------------------
__global__ __launch_bounds__(64) void rel_kernel(
    const float* __restrict__ freqs,
    const float* __restrict__ W1,
    const float* __restrict__ b1,
    const float* __restrict__ W2,
    float* __restrict__ Aw,
    float* __restrict__ Cw,
    __bf16* __restrict__ W2t)
{
    const int row = blockIdx.x;            // 0..4095
    const int k = threadIdx.x;             // 0..63
    const float f = freqs[row];
    const float L = logf(f + 1e-6f);
    const float base = f * W1[k] + L * W1[RH + k];
    Aw[(size_t)row * RH + k] = base + b1[k];
    Cw[(size_t)row * RH + k] = -base;
    if (row < 16)
        W2t[row * 64 + k] = (row < NH) ? (__bf16)W2[k * NH + row] : (__bf16)0.f;
}

// ---------------------------------------------------------------------------
// MFMA bias MLP v3:  bias[b,h,i,j] = sum_k relu(A[i,k]+C[j,k]) * W2[k,h]
// Operand-role swap vs v2: hidden is the A-fragment (rows = i), W2t the
// B-fragment (cols = h). Consequences:
//  - C fragment per j is wave-uniform 16B chunks -> LDS *broadcast* reads,
//    conflict-free (v2's Cs reads were 8-way bank-conflicted b128)
//  - A fragments live in registers, loaded ONCE per 16-i half
//  - D-frag: lane = (i row = kc*4+rr, h col = il), with 8 contiguous j
//    accumulated in registers -> direct bf16x8 global stores, no LDS bounce
// Block = (b, 32 i, 128 j); grid 1024; 4 waves (wave = 32 j). LDS 35 KB.
// ---------------------------------------------------------------------------
__global__ __launch_bounds__(256) void bias_mfma(
    const float* __restrict__ Aw, const float* __restrict__ Cw,
    const __bf16* __restrict__ W2t, __bf16* __restrict__ biasb)
{
    const int t = threadIdx.x;
    const int wave = t >> 6, lane = t & 63;
    const int il = lane & 15, kc = lane >> 4;
    const int j0 = blockIdx.x * 128;
    const int i0 = blockIdx.y * 32;
    const int b  = blockIdx.z;

    __shared__ __align__(16) float Cs[128][68];

    // stage C rows j0..j0+127 (f32, 64 k each)
    {
        const int jr = t >> 1, half = (t & 1) * 32;
        const float* __restrict__ src = &Cw[((size_t)b * SEQ + j0 + jr) * RH + half];
        #pragma unroll
        for (int q = 0; q < 8; ++q)
            *(float4*)&Cs[jr][half + q * 4] = *(const float4*)(src + q * 4);
    }

    // W2 B-fragments: lane holds W2[k=kc*8+m][h=il] = W2t[il][kc*8+m]
    const bf16x8 w2f0 = *(const bf16x8*)&W2t[il * 64 + kc * 8];
    const bf16x8 w2f1 = *(const bf16x8*)&W2t[il * 64 + 32 + kc * 8];
    __syncthreads();

    #pragma unroll
    for (int ih = 0; ih < 2; ++ih) {
        // hidden A-side: rows i0+ih*16+il, k = kc*8..+7 / 32+kc*8..+7
        const float* __restrict__ ap =
            &Aw[((size_t)b * SEQ + i0 + ih * 16 + il) * RH];
        const float4 a0 = *(const float4*)(ap + kc * 8);
        const float4 a1 = *(const float4*)(ap + kc * 8 + 4);
        const float4 a2 = *(const float4*)(ap + 32 + kc * 8);
        const float4 a3 = *(const float4*)(ap + 32 + kc * 8 + 4);

        #pragma unroll
        for (int jb = 0; jb < 4; ++jb) {
            f32x4 accJ[8];
            #pragma unroll
            for (int jj = 0; jj < 8; ++jj) {
                // C chunk for this j: wave-uniform per kc -> LDS broadcast
                const float* __restrict__ cp =
                    &Cs[wave * 32 + jb * 8 + jj][kc * 8];
                const float4 c0 = *(const float4*)(cp);
                const float4 c1 = *(const float4*)(cp + 4);
                const float4 c2 = *(const float4*)(cp + 32);
                const float4 c3 = *(const float4*)(cp + 36);
                bf16x8 hb0, hb1;
                hb0[0] = (__bf16)fmaxf(a0.x + c0.x, 0.f);
                hb0[1] = (__bf16)fmaxf(a0.y + c0.y, 0.f);
                hb0[2] = (__bf16)fmaxf(a0.z + c0.z, 0.f);
                hb0[3] = (__bf16)fmaxf(a0.w + c0.w, 0.f);
                hb0[4] = (__bf16)fmaxf(a1.x + c1.x, 0.f);
                hb0[5] = (__bf16)fmaxf(a1.y + c1.y, 0.f);
                hb0[6] = (__bf16)fmaxf(a1.z + c1.z, 0.f);
                hb0[7] = (__bf16)fmaxf(a1.w + c1.w, 0.f);
                hb1[0] = (__bf16)fmaxf(a2.x + c2.x, 0.f);
                hb1[1] = (__bf16)fmaxf(a2.y + c2.y, 0.f);
                hb1[2] = (__bf16)fmaxf(a2.z + c2.z, 0.f);
                hb1[3] = (__bf16)fmaxf(a2.w + c2.w, 0.f);
                hb1[4] = (__bf16)fmaxf(a3.x + c3.x, 0.f);
                hb1[5] = (__bf16)fmaxf(a3.y + c3.y, 0.f);
                hb1[6] = (__bf16)fmaxf(a3.z + c3.z, 0.f);
                hb1[7] = (__bf16)fmaxf(a3.w + c3.w, 0.f);
                f32x4 acc = {0.f, 0.f, 0.f, 0.f};
                acc = __builtin_amdgcn_mfma_f32_16x16x32_bf16(hb0, w2f0, acc, 0, 0, 0);
                acc = __builtin_amdgcn_mfma_f32_16x16x32_bf16(hb1, w2f1, acc, 0, 0, 0);
                accJ[jj] = acc;
            }
            // D-frag: row i = kc*4+rr, col h = il (il<8 useful), 8 j in regs
            if (il < 8) {
                #pragma unroll
                for (int rr = 0; rr < 4; ++rr) {
                    bf16x8 pv;
                    #pragma unroll
                    for (int jj = 0; jj < 8; ++jj)
                        pv[jj] = (__bf16)accJ[jj][rr];
                    *(bf16x8*)&biasb[(((size_t)b * NH + il) * SEQ
                                      + i0 + ih * 16 + kc * 4 + rr) * SEQ
                                     + j0 + wave * 32 + jb * 8] = pv;
                }
            }
        }
    }
}

// ---------------------------------------------------------------------------
// MFMA attention (round-4 version, best measured: ~73.5-76 us).
// ---------------------------------------------------------------------------
#define PSTR 1032    // bf16 P row stride

__global__ __launch_bounds__(512) void attn_mfma(
    const __bf16* __restrict__ Qb, const __bf16* __restrict__ Kb,
    const __bf16* __restrict__ Vtb, const __bf16* __restrict__ biasb,
    __bf16* __restrict__ ctxb)
{
    const int t = threadIdx.x;
    const int wave = t >> 6, lane = t & 63;
    const int r = lane & 15, kc = lane >> 4;
    const int blk = (blockIdx.x & 7) * 256 + (blockIdx.x >> 3);  // XCD swizzle
    const int it = blk & 63;
    const int h  = (blk >> 6) & 7;
    const int b  = blk >> 9;
    const int s0 = it * 16;
    const int bh = b * NH + h;

    __shared__ __align__(16) __bf16 Pb[16 * PSTR];   // 33024 B
    __shared__ __align__(16) float part[1088];       // phase-3 partials
    __shared__ float red[8][16];
    __shared__ float invl[16];

    // ---- bias prefetch, fragment layout: (row kc*4+rr, col wave*128+jt*16+r)
    uint32_t brg[4][8];
    {
        const uint16_t* __restrict__ bb = (const uint16_t*)biasb
            + ((size_t)bh * SEQ + s0 + kc * 4) * SEQ + wave * 128 + r;
        #pragma unroll
        for (int rr = 0; rr < 4; ++rr)
            #pragma unroll
            for (int jt = 0; jt < 8; ++jt)
                brg[rr][jt] = bb[(size_t)rr * SEQ + jt * 16];
    }

    // ---- phase 1: QK^T via MFMA, scores stay in registers
    f32x4 sc[8];
    {
        const __bf16* __restrict__ Qp = Qb + ((size_t)bh * SEQ + s0) * DH;
        const __bf16* __restrict__ Kp = Kb + ((size_t)bh * SEQ + wave * 128) * DH;
        const bf16x8 qa0 = *(const bf16x8*)(Qp + r * DH + kc * 8);
        const bf16x8 qa1 = *(const bf16x8*)(Qp + r * DH + 32 + kc * 8);
        __builtin_amdgcn_s_setprio(1);
        #pragma unroll
        for (int jt = 0; jt < 8; ++jt) {
            const bf16x8 kb0 = *(const bf16x8*)(Kp + (size_t)(jt * 16 + r) * DH + kc * 8);
            const bf16x8 kb1 = *(const bf16x8*)(Kp + (size_t)(jt * 16 + r) * DH + 32 + kc * 8);
            f32x4 a = {0.f, 0.f, 0.f, 0.f};
            a = __builtin_amdgcn_mfma_f32_16x16x32_bf16(qa0, kb0, a, 0, 0, 0);
            a = __builtin_amdgcn_mfma_f32_16x16x32_bf16(qa1, kb1, a, 0, 0, 0);
            sc[jt] = a;
        }
        __builtin_amdgcn_s_setprio(0);
    }

    // ---- phase 1.5: bias add + exp (no-max) + per-row partial sums
    float psum[4] = {0.f, 0.f, 0.f, 0.f};
    #pragma unroll
    for (int jt = 0; jt < 8; ++jt) {
        #pragma unroll
        for (int rr = 0; rr < 4; ++rr) {
            const float s = fmaf(sc[jt][rr], 0.125f,
                                 __uint_as_float(brg[rr][jt] << 16));
            const float p = __expf(fminf(s, 30.f));
            sc[jt][rr] = p;
            psum[rr] += p;
        }
    }
    // reduce across the 16 lanes (r) of each kc group
    #pragma unroll
    for (int mask = 8; mask >= 1; mask >>= 1)
        #pragma unroll
        for (int rr = 0; rr < 4; ++rr)
            psum[rr] += __shfl_xor(psum[rr], mask);
    if (r == 0) {
        #pragma unroll
        for (int rr = 0; rr < 4; ++rr) red[wave][kc * 4 + rr] = psum[rr];
    }
    // write un-normalized P (bf16) to LDS
    #pragma unroll
    for (int jt = 0; jt < 8; ++jt)
        #pragma unroll
        for (int rr = 0; rr < 4; ++rr)
            Pb[(kc * 4 + rr) * PSTR + wave * 128 + jt * 16 + r] = (__bf16)sc[jt][rr];
    __syncthreads();

    if (t < 16) {
        float l = 0.f;
        #pragma unroll
        for (int w = 0; w < 8; ++w) l += red[w][t];
        invl[t] = 1.0f / l;
    }

    // ---- phase 3: P @ V ; wave = (c-tile = wave&3, K-half = wave>>2)
    {
        const int ct = wave & 3, kh = wave >> 2;
        const __bf16* __restrict__ Vp =
            Vtb + ((size_t)bh * DH + ct * 16 + r) * SEQ + kh * 512;
        f32x4 acc = {0.f, 0.f, 0.f, 0.f};
        __builtin_amdgcn_s_setprio(1);
        #pragma unroll 4
        for (int jt = 0; jt < 16; ++jt) {
            const bf16x8 pa = *(const bf16x8*)&Pb[r * PSTR + kh * 512 + jt * 32 + kc * 8];
            const bf16x8 vb = *(const bf16x8*)(Vp + jt * 32 + kc * 8);
            acc = __builtin_amdgcn_mfma_f32_16x16x32_bf16(pa, vb, acc, 0, 0, 0);
        }
        __builtin_amdgcn_s_setprio(0);
        if (kh == 1) {
            #pragma unroll
            for (int rr = 0; rr < 4; ++rr)
                part[ct * 272 + (kc * 4 + rr) * 17 + r] = acc[rr];
        }
        __syncthreads();
        if (kh == 0) {
            #pragma unroll
            for (int rr = 0; rr < 4; ++rr) {
                const int row = kc * 4 + rr;
                const float v = (acc[rr] + part[ct * 272 + row * 17 + r]) * invl[row];
                ctxb[((size_t)(b * SEQ) + s0 + row) * DM + h * DH + ct * 16 + r] = (__bf16)v;
            }
        }
    }
}

// ---------------------------------------------------------------------------
extern "C" void kernel_launch(void* const* d_in, const int* in_sizes, int n_in,
                              void* d_out, int out_size, void* d_ws, size_t ws_size,
                              hipStream_t stream)
{
    const float* x     = (const float*)d_in[0];
    const float* freqs = (const float*)d_in[1];
    const float* Wq    = (const float*)d_in[2];
    const float* bq    = (const float*)d_in[3];
    const float* Wk    = (const float*)d_in[4];
    const float* bk    = (const float*)d_in[5];
    const float* Wv    = (const float*)d_in[6];
    const float* bv    = (const float*)d_in[7];
    const float* Wo    = (const float*)d_in[8];
    const float* bo    = (const float*)d_in[9];
    const float* W1    = (const float*)d_in[10];
    const float* b1    = (const float*)d_in[11];
    const float* W2    = (const float*)d_in[12];
    // b2 (d_in[13]) is softmax-invariant: dropped.

    char* wsb = (char*)d_ws;
    __bf16* Qb    = (__bf16*)(wsb + QB_OFF);
    __bf16* Kb    = (__bf16*)(wsb + KB_OFF);
    __bf16* Vtb   = (__bf16*)(wsb + VT_OFF);
    __bf16* xb    = (__bf16*)(wsb + XB_OFF);
    __bf16* Wt    = (__bf16*)(wsb + WT_OFF);
    __bf16* Wot   = (__bf16*)(wsb + WOT_OFF);
    __bf16* W2t   = (__bf16*)(wsb + W2T_OFF);
    float*  Aw    = (float*)(wsb + AW_OFF);
    float*  Cw    = (float*)(wsb + CW_OFF);
    __bf16* ctxb  = (__bf16*)(wsb + CTXB_OFF);
    __bf16* biasb = (__bf16*)(wsb + BIAS_OFF);
    float* out = (float*)d_out;

    cast_x<<<dim3(1024), 256, 0, stream>>>(x, xb);
    cast_w<<<dim3(8, 8, 4), 256, 0, stream>>>(Wq, Wk, Wv, Wo, Wt, Wot);
    rel_kernel<<<dim3(4096), 64, 0, stream>>>(freqs, W1, b1, W2, Aw, Cw, W2t);
    gemm_qkv_mfma<<<dim3(12, 32), 256, 0, stream>>>(xb, Wt, bq, bk, bv, Qb, Kb, Vtb);
    bias_mfma<<<dim3(8, 32, 4), 256, 0, stream>>>(Aw, Cw, W2t, biasb);
    attn_mfma<<<dim3(2048), 512, 0, stream>>>(Qb, Kb, Vtb, biasb, ctxb);
    gemm_out_mfma<<<dim3(4, 32), 256, 0, stream>>>(ctxb, Wot, bo, out);
}

// Round 9
// 221.087 us; speedup vs baseline: 1.0099x; 1.0099x over previous
//
#include <hip/hip_runtime.h>
#include <hip/hip_bf16.h>
#include <cstdint>

// Problem constants
#define BATCH   4
#define SEQ     1024
#define DM      512
#define NH      8
#define DH      64
#define RH      64

typedef float f32x4 __attribute__((ext_vector_type(4)));
typedef __bf16 bf16x8 __attribute__((ext_vector_type(8)));

// workspace byte offsets (ws is 256 MiB)
#define QB_OFF    (0)               // bf16 [B][NH][S][DH]   4 MB
#define KB_OFF    (4  << 20)        // bf16 [B][NH][S][DH]   4 MB
#define VT_OFF    (8  << 20)        // bf16 [B][NH][DH][S]   4 MB
#define XB_OFF    (12 << 20)        // bf16 [B*S][DM]        4 MB
#define WT_OFF    (16 << 20)        // bf16 [1536][512] (n,k) 1.5 MB
#define WOT_OFF   (18 << 20)        // bf16 [512][512]  (n,k) 0.5 MB
#define W2T_OFF   (19 << 20)        // bf16 [16][64] (h,k), rows 8..15 = 0
#define AW_OFF    (20 << 20)        // f32  [B*S][RH]        1 MB
#define CW_OFF    (21 << 20)        // f32  [B*S][RH]        1 MB
#define CTXB_OFF  (22 << 20)        // bf16 [B*S][DM]        4 MB

// ---------------------------------------------------------------------------
// cast x (f32 -> bf16)
// ---------------------------------------------------------------------------
__global__ __launch_bounds__(256) void cast_x(
    const float* __restrict__ x, __bf16* __restrict__ xb)
{
    const size_t i = ((size_t)blockIdx.x * 256 + threadIdx.x) * 8;
    const float4 a = *(const float4*)&x[i];
    const float4 b = *(const float4*)&x[i + 4];
    bf16x8 o;
    o[0] = (__bf16)a.x; o[1] = (__bf16)a.y; o[2] = (__bf16)a.z; o[3] = (__bf16)a.w;
    o[4] = (__bf16)b.x; o[5] = (__bf16)b.y; o[6] = (__bf16)b.z; o[7] = (__bf16)b.w;
    *(bf16x8*)&xb[i] = o;
}

// ---------------------------------------------------------------------------
// cast + transpose weights: W[k][n] f32 -> Wt[n][k] bf16.
// ---------------------------------------------------------------------------
__global__ __launch_bounds__(256) void cast_w(
    const float* __restrict__ Wq, const float* __restrict__ Wk,
    const float* __restrict__ Wv, const float* __restrict__ Wo,
    __bf16* __restrict__ Wt, __bf16* __restrict__ Wot)
{
    const int t = threadIdx.x;
    const int k0 = blockIdx.x * 64;
    const int n0 = blockIdx.y * 64;
    const int z  = blockIdx.z;
    const float* __restrict__ src = (z == 0) ? Wq : (z == 1) ? Wk : (z == 2) ? Wv : Wo;
    __bf16* __restrict__ dst = (z < 3) ? (Wt + (size_t)(z * 512 + n0) * 512)
                                       : (Wot + (size_t)n0 * 512);

    __shared__ __align__(16) float Ts[64][65];
    #pragma unroll
    for (int i = 0; i < 4; ++i) {
        const int id = t + i * 256;           // 0..1023
        const int row = id >> 4, c4 = (id & 15) * 4;
        const float4 v = *(const float4*)&src[(size_t)(k0 + row) * DM + n0 + c4];
        Ts[row][c4 + 0] = v.x; Ts[row][c4 + 1] = v.y;
        Ts[row][c4 + 2] = v.z; Ts[row][c4 + 3] = v.w;
    }
    __syncthreads();
    #pragma unroll
    for (int i = 0; i < 2; ++i) {
        const int id = t + i * 256;           // 0..511
        const int rn = id >> 3, ck = (id & 7) * 8;
        bf16x8 o;
        #pragma unroll
        for (int j = 0; j < 8; ++j) o[j] = (__bf16)Ts[ck + j][rn];
        *(bf16x8*)&dst[(size_t)rn * 512 + k0 + ck] = o;
    }
}

// ---------------------------------------------------------------------------
// MFMA GEMM (QKV). XCD-swizzled grid (384 blocks).
// ---------------------------------------------------------------------------
__global__ __launch_bounds__(256) void gemm_qkv_mfma(
    const __bf16* __restrict__ xb, const __bf16* __restrict__ Wt,
    const float* __restrict__ bq, const float* __restrict__ bk,
    const float* __restrict__ bv,
    __bf16* __restrict__ Qb, __bf16* __restrict__ Kb, __bf16* __restrict__ Vtb)
{
    const int t = threadIdx.x;
    const int wave = t >> 6, lane = t & 63;
    const int wm = wave >> 1, wn = wave & 1;
    const int r = lane & 15, kc = lane >> 4, q4 = kc * 4;
    const int lin = blockIdx.y * 12 + blockIdx.x;            // 0..383
    const int swz = (lin & 7) * 48 + (lin >> 3);             // XCD-contiguous
    const int m0 = (swz / 12) * 128;
    const int n0 = (swz % 12) * 128;          // 0..1535
    const int sec = n0 >> 9;                  // 0=Q 1=K 2=V
    const int nn = n0 & 511;

    __shared__ __align__(16) char smem[36864];
    __bf16* __restrict__ As = (__bf16*)smem;            // [128][72]
    __bf16* __restrict__ Bs = (__bf16*)(smem + 18432);  // [128][72]

    f32x4 acc[4][4];
    #pragma unroll
    for (int i = 0; i < 4; ++i)
        #pragma unroll
        for (int j = 0; j < 4; ++j) acc[i][j] = {0.f, 0.f, 0.f, 0.f};

    const int srow = t >> 3, sck = (t & 7) * 8;
    const __bf16* __restrict__ Ag = xb + (size_t)(m0 + srow) * 512 + sck;
    const __bf16* __restrict__ Bg = Wt + (size_t)(n0 + srow) * 512 + sck;

    for (int k0 = 0; k0 < 512; k0 += 64) {
        bf16x8 ra[4], rb[4];
        #pragma unroll
        for (int i = 0; i < 4; ++i) {
            ra[i] = *(const bf16x8*)(Ag + (size_t)i * 32 * 512 + k0);
            rb[i] = *(const bf16x8*)(Bg + (size_t)i * 32 * 512 + k0);
        }
        __syncthreads();
        #pragma unroll
        for (int i = 0; i < 4; ++i) {
            *(bf16x8*)&As[(srow + i * 32) * 72 + sck] = ra[i];
            *(bf16x8*)&Bs[(srow + i * 32) * 72 + sck] = rb[i];
        }
        __syncthreads();
        #pragma unroll
        for (int ks = 0; ks < 2; ++ks) {
            bf16x8 af[4], bf[4];
            #pragma unroll
            for (int mf = 0; mf < 4; ++mf)
                af[mf] = *(const bf16x8*)&As[(wm * 64 + mf * 16 + r) * 72 + ks * 32 + kc * 8];
            #pragma unroll
            for (int nf = 0; nf < 4; ++nf)
                bf[nf] = *(const bf16x8*)&Bs[(wn * 64 + nf * 16 + r) * 72 + ks * 32 + kc * 8];
            #pragma unroll
            for (int mf = 0; mf < 4; ++mf)
                #pragma unroll
                for (int nf = 0; nf < 4; ++nf)
                    acc[mf][nf] = __builtin_amdgcn_mfma_f32_16x16x32_bf16(
                        af[mf], bf[nf], acc[mf][nf], 0, 0, 0);
        }
    }

    const float* __restrict__ bias = (sec == 0) ? bq : (sec == 1) ? bk : bv;
    __syncthreads();
    __bf16* __restrict__ Ls = (__bf16*)smem;            // [128][136]
    if (sec < 2) {
        #pragma unroll
        for (int mf = 0; mf < 4; ++mf)
            #pragma unroll
            for (int nf = 0; nf < 4; ++nf) {
                const int n_l = wn * 64 + nf * 16 + r;
                const float bb = bias[nn + n_l];
                #pragma unroll
                for (int rr = 0; rr < 4; ++rr)
                    Ls[(wm * 64 + mf * 16 + q4 + rr) * 136 + n_l] =
                        (__bf16)(acc[mf][nf][rr] + bb);
            }
    } else {
        #pragma unroll
        for (int mf = 0; mf < 4; ++mf)
            #pragma unroll
            for (int nf = 0; nf < 4; ++nf) {
                const int n_l = wn * 64 + nf * 16 + r;
                const float bb = bias[nn + n_l];
                #pragma unroll
                for (int rr = 0; rr < 4; ++rr)
                    Ls[n_l * 136 + (wm * 64 + mf * 16 + q4 + rr)] =
                        (__bf16)(acc[mf][nf][rr] + bb);
            }
    }
    __syncthreads();

    const int b = m0 >> 10, sbase = m0 & 1023;
    if (sec < 2) {
        __bf16* __restrict__ dst = sec ? Kb : Qb;
        #pragma unroll
        for (int i = 0; i < 8; ++i) {
            const int id = t + i * 256;
            const int row = id >> 4, nc = (id & 15) * 8;
            const bf16x8 v = *(const bf16x8*)&Ls[row * 136 + nc];
            const int ng = nn + nc, h = ng >> 6, c = ng & 63;
            *(bf16x8*)&dst[((size_t)(b * NH + h) * SEQ + sbase + row) * DH + c] = v;
        }
    } else {
        #pragma unroll
        for (int i = 0; i < 8; ++i) {
            const int id = t + i * 256;
            const int nrow = id >> 4, mc = (id & 15) * 8;
            const bf16x8 v = *(const bf16x8*)&Ls[nrow * 136 + mc];
            const int ng = nn + nrow, h = ng >> 6, c = ng & 63;
            *(bf16x8*)&Vtb[((size_t)(b * NH + h) * DH + c) * SEQ + sbase + mc] = v;
        }
    }
}

// ---------------------------------------------------------------------------
// MFMA GEMM (out). XCD-swizzled grid (128 blocks).
// ---------------------------------------------------------------------------
__global__ __launch_bounds__(256) void gemm_out_mfma(
    const __bf16* __restrict__ ctxb, const __bf16* __restrict__ Wot,
    const float* __restrict__ bo, float* __restrict__ out)
{
    const int t = threadIdx.x;
    const int wave = t >> 6, lane = t & 63;
    const int wm = wave >> 1, wn = wave & 1;
    const int r = lane & 15, kc = lane >> 4, q4 = kc * 4;
    const int lin = blockIdx.y * 4 + blockIdx.x;             // 0..127
    const int swz = (lin & 7) * 16 + (lin >> 3);
    const int m0 = (swz / 4) * 128;
    const int n0 = (swz % 4) * 128;

    __shared__ __align__(16) char smem[36864];
    __bf16* __restrict__ As = (__bf16*)smem;
    __bf16* __restrict__ Bs = (__bf16*)(smem + 18432);

    f32x4 acc[4][4];
    #pragma unroll
    for (int i = 0; i < 4; ++i)
        #pragma unroll
        for (int j = 0; j < 4; ++j) acc[i][j] = {0.f, 0.f, 0.f, 0.f};

    const int srow = t >> 3, sck = (t & 7) * 8;
    const __bf16* __restrict__ Ag = ctxb + (size_t)(m0 + srow) * 512 + sck;
    const __bf16* __restrict__ Bg = Wot + (size_t)(n0 + srow) * 512 + sck;

    for (int k0 = 0; k0 < 512; k0 += 64) {
        bf16x8 ra[4], rb[4];
        #pragma unroll
        for (int i = 0; i < 4; ++i) {
            ra[i] = *(const bf16x8*)(Ag + (size_t)i * 32 * 512 + k0);
            rb[i] = *(const bf16x8*)(Bg + (size_t)i * 32 * 512 + k0);
        }
        __syncthreads();
        #pragma unroll
        for (int i = 0; i < 4; ++i) {
            *(bf16x8*)&As[(srow + i * 32) * 72 + sck] = ra[i];
            *(bf16x8*)&Bs[(srow + i * 32) * 72 + sck] = rb[i];
        }
        __syncthreads();
        #pragma unroll
        for (int ks = 0; ks < 2; ++ks) {
            bf16x8 af[4], bf[4];
            #pragma unroll
            for (int mf = 0; mf < 4; ++mf)
                af[mf] = *(const bf16x8*)&As[(wm * 64 + mf * 16 + r) * 72 + ks * 32 + kc * 8];
            #pragma unroll
            for (int nf = 0; nf < 4; ++nf)
                bf[nf] = *(const bf16x8*)&Bs[(wn * 64 + nf * 16 + r) * 72 + ks * 32 + kc * 8];
            #pragma unroll
            for (int mf = 0; mf < 4; ++mf)
                #pragma unroll
                for (int nf = 0; nf < 4; ++nf)
                    acc[mf][nf] = __builtin_amdgcn_mfma_f32_16x16x32_bf16(
                        af[mf], bf[nf], acc[mf][nf], 0, 0, 0);
        }
    }

    #pragma unroll
    for (int mf = 0; mf < 4; ++mf)
        #pragma unroll
        for (int nf = 0; nf < 4; ++nf) {
            const int n_l = wn * 64 + nf * 16 + r;
            const float bb = bo[n0 + n_l];
            #pragma unroll
            for (int rr = 0; rr < 4; ++rr)
                out[(size_t)(m0 + wm * 64 + mf * 16 + q4 + rr) * DM + n0 + n_l] =
                    acc[mf][nf][rr] + bb;
        }
}

// ---------------------------------------------------------------------------
// Relative-feature precompute + W2t emit (blocks 0..15)
// ---------------------------------------------------------------------------
__global__ __launch_bounds__(64) void rel_kernel(
    const float* __restrict__ freqs,
    const float* __restrict__ W1,
    const float* __restrict__ b1,
    const float* __restrict__ W2,
    float* __restrict__ Aw,
    float* __restrict__ Cw,
    __bf16* __restrict__ W2t)
{
    const int row = blockIdx.x;            // 0..4095
    const int k = threadIdx.x;             // 0..63
    const float f = freqs[row];
    const float L = logf(f + 1e-6f);
    const float base = f * W1[k] + L * W1[RH + k];
    Aw[(size_t)row * RH + k] = base + b1[k];
    Cw[(size_t)row * RH + k] = -base;
    if (row < 16)
        W2t[row * 64 + k] = (row < NH) ? (__bf16)W2[k * NH + row] : (__bf16)0.f;
}

// ---------------------------------------------------------------------------
// FUSED attention + bias-MLP. Block = (b, 16-q tile) -> 256 blocks, 8 waves,
// wave = head. The 64 MB bias tensor is never materialized: per 128-j chunk,
// the hidden relu(A_i + C_j) is built ONCE (cooperatively, v3's verified
// fragment math) and projected through W2t into an LDS plane [8h][16q][128j],
// which each head-wave consumes (bias add + no-max exp), overwrites in place
// as P, then PV-accumulates O in registers. psum/O wave-local across chunks;
// normalization needs no cross-wave combine.
// LDS: Cs 34.8 KB + BsP 33.9 KB = 68.7 KB. 2 barriers per chunk.
// ---------------------------------------------------------------------------
#define HSTR 2120   // bf16 plane stride per head (16*132 + 8: bank-spread)
#define JSTR 132    // bf16 row stride within plane

__global__ __launch_bounds__(512) void attn_fused(
    const __bf16* __restrict__ Qb, const __bf16* __restrict__ Kb,
    const __bf16* __restrict__ Vtb, const float* __restrict__ Aw,
    const float* __restrict__ Cw, const __bf16* __restrict__ W2t,
    __bf16* __restrict__ ctxb)
{
    const int t = threadIdx.x;
    const int wave = t >> 6, lane = t & 63;      // wave = head h
    const int r = lane & 15, kc = lane >> 4;
    const int il = r;                             // build-phase i/h index
    const int blk = (blockIdx.x & 7) * 32 + (blockIdx.x >> 3);  // XCD swizzle
    const int qt = blk & 63;
    const int b  = blk >> 6;
    const int s0 = qt * 16;
    const int bh = b * NH + wave;

    __shared__ __align__(16) float  Cs[128 * 68];     // 34816 B
    __shared__ __align__(16) __bf16 BsP[8 * HSTR];    // 33920 B

    // ---- per-thread constants (whole kernel) ----
    // Q fragments for this wave's head
    const __bf16* __restrict__ Qp = Qb + ((size_t)bh * SEQ + s0) * DH;
    const bf16x8 qa0 = *(const bf16x8*)(Qp + r * DH + kc * 8);
    const bf16x8 qa1 = *(const bf16x8*)(Qp + r * DH + 32 + kc * 8);
    // A-side hidden inputs: row il (= q-row), k = kc*8.. (build phase)
    const float* __restrict__ ap = &Aw[((size_t)b * SEQ + s0 + il) * RH];
    const float4 a0 = *(const float4*)(ap + kc * 8);
    const float4 a1 = *(const float4*)(ap + kc * 8 + 4);
    const float4 a2 = *(const float4*)(ap + 32 + kc * 8);
    const float4 a3 = *(const float4*)(ap + 32 + kc * 8 + 4);
    // W2t B-fragments: lane il holds column h=il
    const bf16x8 w2f0 = *(const bf16x8*)&W2t[il * 64 + kc * 8];
    const bf16x8 w2f1 = *(const bf16x8*)&W2t[il * 64 + 32 + kc * 8];

    float psum[4] = {0.f, 0.f, 0.f, 0.f};
    f32x4 O[4];
    #pragma unroll
    for (int ct = 0; ct < 4; ++ct) O[ct] = {0.f, 0.f, 0.f, 0.f};

    const __bf16* __restrict__ KpB = Kb + (size_t)bh * SEQ * DH;
    const int crow = t >> 2, cseg = (t & 3) * 16;   // Cs staging role

    for (int c = 0; c < 8; ++c) {
        const int j0 = c * 128;

        // ---- QK^T for this head (16q x 128j), scores to regs
        f32x4 sc[8];
        {
            const __bf16* __restrict__ Kp = KpB + (size_t)j0 * DH;
            __builtin_amdgcn_s_setprio(1);
            #pragma unroll
            for (int jt = 0; jt < 8; ++jt) {
                const bf16x8 kb0 = *(const bf16x8*)(Kp + (size_t)(jt * 16 + r) * DH + kc * 8);
                const bf16x8 kb1 = *(const bf16x8*)(Kp + (size_t)(jt * 16 + r) * DH + 32 + kc * 8);
                f32x4 a = {0.f, 0.f, 0.f, 0.f};
                a = __builtin_amdgcn_mfma_f32_16x16x32_bf16(qa0, kb0, a, 0, 0, 0);
                a = __builtin_amdgcn_mfma_f32_16x16x32_bf16(qa1, kb1, a, 0, 0, 0);
                sc[jt] = a;
            }
            __builtin_amdgcn_s_setprio(0);
        }

        // ---- stage C rows j0..j0+127 into Cs (all waves)
        {
            const float* __restrict__ src =
                &Cw[((size_t)b * SEQ + j0 + crow) * RH + cseg];
            #pragma unroll
            for (int q = 0; q < 4; ++q)
                *(float4*)&Cs[crow * 68 + cseg + q * 4] =
                    *(const float4*)(src + q * 4);
        }
        __syncthreads();   // Cs ready; prev-chunk PV done (BsP free)

        // ---- cooperative bias build: wave handles its 16-j group
        #pragma unroll
        for (int jj = 0; jj < 16; ++jj) {
            const int jl = wave * 16 + jj;
            const float* __restrict__ cp = &Cs[jl * 68 + kc * 8];
            const float4 c0 = *(const float4*)(cp);
            const float4 c1 = *(const float4*)(cp + 4);
            const float4 c2 = *(const float4*)(cp + 32);
            const float4 c3 = *(const float4*)(cp + 36);
            bf16x8 hb0, hb1;
            hb0[0] = (__bf16)fmaxf(a0.x + c0.x, 0.f);
            hb0[1] = (__bf16)fmaxf(a0.y + c0.y, 0.f);
            hb0[2] = (__bf16)fmaxf(a0.z + c0.z, 0.f);
            hb0[3] = (__bf16)fmaxf(a0.w + c0.w, 0.f);
            hb0[4] = (__bf16)fmaxf(a1.x + c1.x, 0.f);
            hb0[5] = (__bf16)fmaxf(a1.y + c1.y, 0.f);
            hb0[6] = (__bf16)fmaxf(a1.z + c1.z, 0.f);
            hb0[7] = (__bf16)fmaxf(a1.w + c1.w, 0.f);
            hb1[0] = (__bf16)fmaxf(a2.x + c2.x, 0.f);
            hb1[1] = (__bf16)fmaxf(a2.y + c2.y, 0.f);
            hb1[2] = (__bf16)fmaxf(a2.z + c2.z, 0.f);
            hb1[3] = (__bf16)fmaxf(a2.w + c2.w, 0.f);
            hb1[4] = (__bf16)fmaxf(a3.x + c3.x, 0.f);
            hb1[5] = (__bf16)fmaxf(a3.y + c3.y, 0.f);
            hb1[6] = (__bf16)fmaxf(a3.z + c3.z, 0.f);
            hb1[7] = (__bf16)fmaxf(a3.w + c3.w, 0.f);
            f32x4 acc = {0.f, 0.f, 0.f, 0.f};
            acc = __builtin_amdgcn_mfma_f32_16x16x32_bf16(hb0, w2f0, acc, 0, 0, 0);
            acc = __builtin_amdgcn_mfma_f32_16x16x32_bf16(hb1, w2f1, acc, 0, 0, 0);
            // D: row = i = kc*4+rr, col = h = il (il<8 valid)
            if (il < 8) {
                #pragma unroll
                for (int rr = 0; rr < 4; ++rr)
                    BsP[il * HSTR + (kc * 4 + rr) * JSTR + jl] = (__bf16)acc[rr];
            }
        }
        __syncthreads();   // bias plane complete

        // ---- bias add + exp (no-max), overwrite BsP in place as P
        #pragma unroll
        for (int jt = 0; jt < 8; ++jt) {
            #pragma unroll
            for (int rr = 0; rr < 4; ++rr) {
                const int idx = wave * HSTR + (kc * 4 + rr) * JSTR + jt * 16 + r;
                const float s = fmaf(sc[jt][rr], 0.125f, (float)BsP[idx]);
                const float p = __expf(fminf(s, 30.f));
                psum[rr] += p;
                BsP[idx] = (__bf16)p;   // same thread, same index: safe overlay
            }
        }
        // wave-internal LDS write->read ordering before PV
        asm volatile("s_waitcnt lgkmcnt(0)" ::: "memory");
        __builtin_amdgcn_sched_barrier(0);

        // ---- PV for this head over the chunk; O accumulates across chunks
        {
            __builtin_amdgcn_s_setprio(1);
            #pragma unroll
            for (int ct = 0; ct < 4; ++ct) {
                const __bf16* __restrict__ Vp =
                    Vtb + ((size_t)bh * DH + ct * 16 + r) * SEQ + j0;
                #pragma unroll
                for (int js = 0; js < 4; ++js) {
                    const bf16x8 pa = *(const bf16x8*)
                        &BsP[wave * HSTR + r * JSTR + js * 32 + kc * 8];
                    const bf16x8 vb = *(const bf16x8*)(Vp + js * 32 + kc * 8);
                    O[ct] = __builtin_amdgcn_mfma_f32_16x16x32_bf16(pa, vb, O[ct], 0, 0, 0);
                }
            }
            __builtin_amdgcn_s_setprio(0);
        }
        __syncthreads();   // PV done: next chunk may rebuild BsP / restage Cs
    }

    // ---- normalize + write ctx (all wave-local: rows q = kc*4+rr)
    #pragma unroll
    for (int mask = 8; mask >= 1; mask >>= 1)
        #pragma unroll
        for (int rr = 0; rr < 4; ++rr)
            psum[rr] += __shfl_xor(psum[rr], mask);
    #pragma unroll
    for (int rr = 0; rr < 4; ++rr) {
        const float inv = 1.0f / psum[rr];
        const int q = s0 + kc * 4 + rr;
        #pragma unroll
        for (int ct = 0; ct < 4; ++ct)
            ctxb[((size_t)(b * SEQ) + q) * DM + wave * DH + ct * 16 + r] =
                (__bf16)(O[ct][rr] * inv);
    }
}

// ---------------------------------------------------------------------------
extern "C" void kernel_launch(void* const* d_in, const int* in_sizes, int n_in,
                              void* d_out, int out_size, void* d_ws, size_t ws_size,
                              hipStream_t stream)
{
    const float* x     = (const float*)d_in[0];
    const float* freqs = (const float*)d_in[1];
    const float* Wq    = (const float*)d_in[2];
    const float* bq    = (const float*)d_in[3];
    const float* Wk    = (const float*)d_in[4];
    const float* bk    = (const float*)d_in[5];
    const float* Wv    = (const float*)d_in[6];
    const float* bv    = (const float*)d_in[7];
    const float* Wo    = (const float*)d_in[8];
    const float* bo    = (const float*)d_in[9];
    const float* W1    = (const float*)d_in[10];
    const float* b1    = (const float*)d_in[11];
    const float* W2    = (const float*)d_in[12];
    // b2 (d_in[13]) is softmax-invariant: dropped.

    char* wsb = (char*)d_ws;
    __bf16* Qb    = (__bf16*)(wsb + QB_OFF);
    __bf16* Kb    = (__bf16*)(wsb + KB_OFF);
    __bf16* Vtb   = (__bf16*)(wsb + VT_OFF);
    __bf16* xb    = (__bf16*)(wsb + XB_OFF);
    __bf16* Wt    = (__bf16*)(wsb + WT_OFF);
    __bf16* Wot   = (__bf16*)(wsb + WOT_OFF);
    __bf16* W2t   = (__bf16*)(wsb + W2T_OFF);
    float*  Aw    = (float*)(wsb + AW_OFF);
    float*  Cw    = (float*)(wsb + CW_OFF);
    __bf16* ctxb  = (__bf16*)(wsb + CTXB_OFF);
    float* out = (float*)d_out;

    cast_x<<<dim3(1024), 256, 0, stream>>>(x, xb);
    cast_w<<<dim3(8, 8, 4), 256, 0, stream>>>(Wq, Wk, Wv, Wo, Wt, Wot);
    rel_kernel<<<dim3(4096), 64, 0, stream>>>(freqs, W1, b1, W2, Aw, Cw, W2t);
    gemm_qkv_mfma<<<dim3(12, 32), 256, 0, stream>>>(xb, Wt, bq, bk, bv, Qb, Kb, Vtb);
    attn_fused<<<dim3(256), 512, 0, stream>>>(Qb, Kb, Vtb, Aw, Cw, W2t, ctxb);
    gemm_out_mfma<<<dim3(4, 32), 256, 0, stream>>>(ctxb, Wot, bo, out);
}

// Round 10
// 207.744 us; speedup vs baseline: 1.0748x; 1.0642x over previous
//
#include <hip/hip_runtime.h>
#include <hip/hip_bf16.h>
#include <cstdint>

// Problem constants
#define BATCH   4
#define SEQ     1024
#define DM      512
#define NH      8
#define DH      64
#define RH      64

typedef float f32x4 __attribute__((ext_vector_type(4)));
typedef __bf16 bf16x8 __attribute__((ext_vector_type(8)));

// workspace byte offsets (ws is 256 MiB)
#define QB_OFF    (0)               // bf16 [B][NH][S][DH]   4 MB
#define KB_OFF    (4  << 20)        // bf16 [B][NH][S][DH]   4 MB
#define VT_OFF    (8  << 20)        // bf16 [B][NH][DH][S]   4 MB
#define XB_OFF    (12 << 20)        // bf16 [B*S][DM]        4 MB
#define WT_OFF    (16 << 20)        // bf16 [1536][512] (n,k) 1.5 MB
#define WOT_OFF   (18 << 20)        // bf16 [512][512]  (n,k) 0.5 MB
#define W2T_OFF   (19 << 20)        // bf16 [16][64] (h,k), rows 8..15 = 0
#define AW_OFF    (20 << 20)        // f32  [B*S][RH]        1 MB
#define CW_OFF    (21 << 20)        // f32  [B*S][RH]        1 MB
#define CTXB_OFF  (22 << 20)        // bf16 [B*S][DM]        4 MB
#define BIAS_OFF  (32 << 20)        // bf16 [B][NH][S][S]   64 MB

// ---------------------------------------------------------------------------
// PROLOGUE (horizontal fusion, 1 launch):
//   blocks    0..1023 : cast x f32->bf16
//   blocks 1024..1279 : cast+transpose weights (Wq,Wk,Wv -> Wt; Wo -> Wot)
//   blocks 1280..2303 : rel features (Aw, Cw) + W2t emit
// All parts are mutually independent.
// ---------------------------------------------------------------------------
__global__ __launch_bounds__(256) void prologue(
    const float* __restrict__ x,
    const float* __restrict__ Wq, const float* __restrict__ Wk,
    const float* __restrict__ Wv, const float* __restrict__ Wo,
    const float* __restrict__ freqs, const float* __restrict__ W1,
    const float* __restrict__ b1, const float* __restrict__ W2,
    __bf16* __restrict__ xb, __bf16* __restrict__ Wt,
    __bf16* __restrict__ Wot, float* __restrict__ Aw,
    float* __restrict__ Cw, __bf16* __restrict__ W2t)
{
    const int t = threadIdx.x;
    const int id = blockIdx.x;
    __shared__ __align__(16) float Ts[64][65];

    if (id < 1024) {
        // ---- cast x
        const size_t i = ((size_t)id * 256 + t) * 8;
        const float4 a = *(const float4*)&x[i];
        const float4 b = *(const float4*)&x[i + 4];
        bf16x8 o;
        o[0] = (__bf16)a.x; o[1] = (__bf16)a.y; o[2] = (__bf16)a.z; o[3] = (__bf16)a.w;
        o[4] = (__bf16)b.x; o[5] = (__bf16)b.y; o[6] = (__bf16)b.z; o[7] = (__bf16)b.w;
        *(bf16x8*)&xb[i] = o;
    } else if (id < 1280) {
        // ---- cast + transpose weights (64x64 tile via LDS bounce)
        const int lin = id - 1024;          // 0..255
        const int z   = lin >> 6;           // 0..3
        const int rem = lin & 63;
        const int k0  = (rem >> 3) * 64;
        const int n0  = (rem & 7) * 64;
        const float* __restrict__ src = (z == 0) ? Wq : (z == 1) ? Wk
                                       : (z == 2) ? Wv : Wo;
        __bf16* __restrict__ dst = (z < 3) ? (Wt + (size_t)(z * 512 + n0) * 512)
                                           : (Wot + (size_t)n0 * 512);
        #pragma unroll
        for (int i = 0; i < 4; ++i) {
            const int iid = t + i * 256;
            const int row = iid >> 4, c4 = (iid & 15) * 4;
            const float4 v = *(const float4*)&src[(size_t)(k0 + row) * DM + n0 + c4];
            Ts[row][c4 + 0] = v.x; Ts[row][c4 + 1] = v.y;
            Ts[row][c4 + 2] = v.z; Ts[row][c4 + 3] = v.w;
        }
        __syncthreads();
        #pragma unroll
        for (int i = 0; i < 2; ++i) {
            const int iid = t + i * 256;
            const int rn = iid >> 3, ck = (iid & 7) * 8;
            bf16x8 o;
            #pragma unroll
            for (int j = 0; j < 8; ++j) o[j] = (__bf16)Ts[ck + j][rn];
            *(bf16x8*)&dst[(size_t)rn * 512 + k0 + ck] = o;
        }
    } else {
        // ---- rel features: 4 rows per block
        const int lin = id - 1280;          // 0..1023
        const int row = lin * 4 + (t >> 6);
        const int k = t & 63;
        const float f = freqs[row];
        const float L = logf(f + 1e-6f);
        const float base = f * W1[k] + L * W1[RH + k];
        Aw[(size_t)row * RH + k] = base + b1[k];
        Cw[(size_t)row * RH + k] = -base;
        if (row < 16)
            W2t[row * 64 + k] = (row < NH) ? (__bf16)W2[k * NH + row] : (__bf16)0.f;
    }
}

// ---------------------------------------------------------------------------
// MID (horizontal fusion, 1 launch): the QKV GEMM and the bias MLP are
// data-independent -> run them concurrently by block-range split.
//   blocks    0..383  : MFMA QKV GEMM (r8 version, XCD-swizzled)
//   blocks  384..1407 : MFMA bias MLP v3 (r8 version)
// 1408 blocks ~= 5.5 blocks/CU: chip stays full instead of two half-empty
// serial kernels.
// ---------------------------------------------------------------------------
__global__ __launch_bounds__(256) void mid_fused(
    const __bf16* __restrict__ xb, const __bf16* __restrict__ Wt,
    const float* __restrict__ bq, const float* __restrict__ bk,
    const float* __restrict__ bv,
    __bf16* __restrict__ Qb, __bf16* __restrict__ Kb, __bf16* __restrict__ Vtb,
    const float* __restrict__ Aw, const float* __restrict__ Cw,
    const __bf16* __restrict__ W2t, __bf16* __restrict__ biasb)
{
    const int t = threadIdx.x;
    __shared__ __align__(16) char smem[36864];

    if (blockIdx.x < 384) {
        // ================= QKV GEMM =================
        const int wave = t >> 6, lane = t & 63;
        const int wm = wave >> 1, wn = wave & 1;
        const int r = lane & 15, kc = lane >> 4, q4 = kc * 4;
        const int lin = blockIdx.x;                              // 0..383
        const int swz = (lin & 7) * 48 + (lin >> 3);             // XCD-contiguous
        const int m0 = (swz / 12) * 128;
        const int n0 = (swz % 12) * 128;          // 0..1535
        const int sec = n0 >> 9;                  // 0=Q 1=K 2=V
        const int nn = n0 & 511;

        __bf16* __restrict__ As = (__bf16*)smem;            // [128][72]
        __bf16* __restrict__ Bs = (__bf16*)(smem + 18432);  // [128][72]

        f32x4 acc[4][4];
        #pragma unroll
        for (int i = 0; i < 4; ++i)
            #pragma unroll
            for (int j = 0; j < 4; ++j) acc[i][j] = {0.f, 0.f, 0.f, 0.f};

        const int srow = t >> 3, sck = (t & 7) * 8;
        const __bf16* __restrict__ Ag = xb + (size_t)(m0 + srow) * 512 + sck;
        const __bf16* __restrict__ Bg = Wt + (size_t)(n0 + srow) * 512 + sck;

        for (int k0 = 0; k0 < 512; k0 += 64) {
            bf16x8 ra[4], rb[4];
            #pragma unroll
            for (int i = 0; i < 4; ++i) {
                ra[i] = *(const bf16x8*)(Ag + (size_t)i * 32 * 512 + k0);
                rb[i] = *(const bf16x8*)(Bg + (size_t)i * 32 * 512 + k0);
            }
            __syncthreads();
            #pragma unroll
            for (int i = 0; i < 4; ++i) {
                *(bf16x8*)&As[(srow + i * 32) * 72 + sck] = ra[i];
                *(bf16x8*)&Bs[(srow + i * 32) * 72 + sck] = rb[i];
            }
            __syncthreads();
            #pragma unroll
            for (int ks = 0; ks < 2; ++ks) {
                bf16x8 af[4], bf[4];
                #pragma unroll
                for (int mf = 0; mf < 4; ++mf)
                    af[mf] = *(const bf16x8*)&As[(wm * 64 + mf * 16 + r) * 72 + ks * 32 + kc * 8];
                #pragma unroll
                for (int nf = 0; nf < 4; ++nf)
                    bf[nf] = *(const bf16x8*)&Bs[(wn * 64 + nf * 16 + r) * 72 + ks * 32 + kc * 8];
                #pragma unroll
                for (int mf = 0; mf < 4; ++mf)
                    #pragma unroll
                    for (int nf = 0; nf < 4; ++nf)
                        acc[mf][nf] = __builtin_amdgcn_mfma_f32_16x16x32_bf16(
                            af[mf], bf[nf], acc[mf][nf], 0, 0, 0);
            }
        }

        const float* __restrict__ bias = (sec == 0) ? bq : (sec == 1) ? bk : bv;
        __syncthreads();
        __bf16* __restrict__ Ls = (__bf16*)smem;            // [128][136]
        if (sec < 2) {
            #pragma unroll
            for (int mf = 0; mf < 4; ++mf)
                #pragma unroll
                for (int nf = 0; nf < 4; ++nf) {
                    const int n_l = wn * 64 + nf * 16 + r;
                    const float bb = bias[nn + n_l];
                    #pragma unroll
                    for (int rr = 0; rr < 4; ++rr)
                        Ls[(wm * 64 + mf * 16 + q4 + rr) * 136 + n_l] =
                            (__bf16)(acc[mf][nf][rr] + bb);
                }
        } else {
            #pragma unroll
            for (int mf = 0; mf < 4; ++mf)
                #pragma unroll
                for (int nf = 0; nf < 4; ++nf) {
                    const int n_l = wn * 64 + nf * 16 + r;
                    const float bb = bias[nn + n_l];
                    #pragma unroll
                    for (int rr = 0; rr < 4; ++rr)
                        Ls[n_l * 136 + (wm * 64 + mf * 16 + q4 + rr)] =
                            (__bf16)(acc[mf][nf][rr] + bb);
                }
        }
        __syncthreads();

        const int b = m0 >> 10, sbase = m0 & 1023;
        if (sec < 2) {
            __bf16* __restrict__ dst = sec ? Kb : Qb;
            #pragma unroll
            for (int i = 0; i < 8; ++i) {
                const int id = t + i * 256;
                const int row = id >> 4, nc = (id & 15) * 8;
                const bf16x8 v = *(const bf16x8*)&Ls[row * 136 + nc];
                const int ng = nn + nc, h = ng >> 6, c = ng & 63;
                *(bf16x8*)&dst[((size_t)(b * NH + h) * SEQ + sbase + row) * DH + c] = v;
            }
        } else {
            #pragma unroll
            for (int i = 0; i < 8; ++i) {
                const int id = t + i * 256;
                const int nrow = id >> 4, mc = (id & 15) * 8;
                const bf16x8 v = *(const bf16x8*)&Ls[nrow * 136 + mc];
                const int ng = nn + nrow, h = ng >> 6, c = ng & 63;
                *(bf16x8*)&Vtb[((size_t)(b * NH + h) * DH + c) * SEQ + sbase + mc] = v;
            }
        }
    } else {
        // ================= bias MLP v3 =================
        const int wave = t >> 6, lane = t & 63;
        const int il = lane & 15, kc = lane >> 4;
        const int id2 = blockIdx.x - 384;        // 0..1023
        const int b   = id2 >> 8;                // 0..3
        const int rem = id2 & 255;
        const int i0  = (rem >> 3) * 32;         // 0..992
        const int j0  = (rem & 7) * 128;         // 0..896

        float* __restrict__ Cs = (float*)smem;   // [128][68] = 34816 B

        // stage C rows j0..j0+127 (f32, 64 k each)
        {
            const int jr = t >> 1, half = (t & 1) * 32;
            const float* __restrict__ src = &Cw[((size_t)b * SEQ + j0 + jr) * RH + half];
            #pragma unroll
            for (int q = 0; q < 8; ++q)
                *(float4*)&Cs[jr * 68 + half + q * 4] = *(const float4*)(src + q * 4);
        }

        // W2 B-fragments: lane holds W2[k=kc*8+m][h=il] = W2t[il][kc*8+m]
        const bf16x8 w2f0 = *(const bf16x8*)&W2t[il * 64 + kc * 8];
        const bf16x8 w2f1 = *(const bf16x8*)&W2t[il * 64 + 32 + kc * 8];
        __syncthreads();

        #pragma unroll
        for (int ih = 0; ih < 2; ++ih) {
            const float* __restrict__ ap =
                &Aw[((size_t)b * SEQ + i0 + ih * 16 + il) * RH];
            const float4 a0 = *(const float4*)(ap + kc * 8);
            const float4 a1 = *(const float4*)(ap + kc * 8 + 4);
            const float4 a2 = *(const float4*)(ap + 32 + kc * 8);
            const float4 a3 = *(const float4*)(ap + 32 + kc * 8 + 4);

            #pragma unroll
            for (int jb = 0; jb < 4; ++jb) {
                f32x4 accJ[8];
                #pragma unroll
                for (int jj = 0; jj < 8; ++jj) {
                    const float* __restrict__ cp =
                        &Cs[(wave * 32 + jb * 8 + jj) * 68 + kc * 8];
                    const float4 c0 = *(const float4*)(cp);
                    const float4 c1 = *(const float4*)(cp + 4);
                    const float4 c2 = *(const float4*)(cp + 32);
                    const float4 c3 = *(const float4*)(cp + 36);
                    bf16x8 hb0, hb1;
                    hb0[0] = (__bf16)fmaxf(a0.x + c0.x, 0.f);
                    hb0[1] = (__bf16)fmaxf(a0.y + c0.y, 0.f);
                    hb0[2] = (__bf16)fmaxf(a0.z + c0.z, 0.f);
                    hb0[3] = (__bf16)fmaxf(a0.w + c0.w, 0.f);
                    hb0[4] = (__bf16)fmaxf(a1.x + c1.x, 0.f);
                    hb0[5] = (__bf16)fmaxf(a1.y + c1.y, 0.f);
                    hb0[6] = (__bf16)fmaxf(a1.z + c1.z, 0.f);
                    hb0[7] = (__bf16)fmaxf(a1.w + c1.w, 0.f);
                    hb1[0] = (__bf16)fmaxf(a2.x + c2.x, 0.f);
                    hb1[1] = (__bf16)fmaxf(a2.y + c2.y, 0.f);
                    hb1[2] = (__bf16)fmaxf(a2.z + c2.z, 0.f);
                    hb1[3] = (__bf16)fmaxf(a2.w + c2.w, 0.f);
                    hb1[4] = (__bf16)fmaxf(a3.x + c3.x, 0.f);
                    hb1[5] = (__bf16)fmaxf(a3.y + c3.y, 0.f);
                    hb1[6] = (__bf16)fmaxf(a3.z + c3.z, 0.f);
                    hb1[7] = (__bf16)fmaxf(a3.w + c3.w, 0.f);
                    f32x4 acc = {0.f, 0.f, 0.f, 0.f};
                    acc = __builtin_amdgcn_mfma_f32_16x16x32_bf16(hb0, w2f0, acc, 0, 0, 0);
                    acc = __builtin_amdgcn_mfma_f32_16x16x32_bf16(hb1, w2f1, acc, 0, 0, 0);
                    accJ[jj] = acc;
                }
                if (il < 8) {
                    #pragma unroll
                    for (int rr = 0; rr < 4; ++rr) {
                        bf16x8 pv;
                        #pragma unroll
                        for (int jj = 0; jj < 8; ++jj)
                            pv[jj] = (__bf16)accJ[jj][rr];
                        *(bf16x8*)&biasb[(((size_t)b * NH + il) * SEQ
                                          + i0 + ih * 16 + kc * 4 + rr) * SEQ
                                         + j0 + wave * 32 + jb * 8] = pv;
                    }
                }
            }
        }
    }
}

// ---------------------------------------------------------------------------
// MFMA attention (r8 version, best measured 72.0 us).
// ---------------------------------------------------------------------------
#define PSTR 1032    // bf16 P row stride

__global__ __launch_bounds__(512) void attn_mfma(
    const __bf16* __restrict__ Qb, const __bf16* __restrict__ Kb,
    const __bf16* __restrict__ Vtb, const __bf16* __restrict__ biasb,
    __bf16* __restrict__ ctxb)
{
    const int t = threadIdx.x;
    const int wave = t >> 6, lane = t & 63;
    const int r = lane & 15, kc = lane >> 4;
    const int blk = (blockIdx.x & 7) * 256 + (blockIdx.x >> 3);  // XCD swizzle
    const int it = blk & 63;
    const int h  = (blk >> 6) & 7;
    const int b  = blk >> 9;
    const int s0 = it * 16;
    const int bh = b * NH + h;

    __shared__ __align__(16) __bf16 Pb[16 * PSTR];   // 33024 B
    __shared__ __align__(16) float part[1088];       // phase-3 partials
    __shared__ float red[8][16];
    __shared__ float invl[16];

    // ---- bias prefetch, fragment layout: (row kc*4+rr, col wave*128+jt*16+r)
    uint32_t brg[4][8];
    {
        const uint16_t* __restrict__ bb = (const uint16_t*)biasb
            + ((size_t)bh * SEQ + s0 + kc * 4) * SEQ + wave * 128 + r;
        #pragma unroll
        for (int rr = 0; rr < 4; ++rr)
            #pragma unroll
            for (int jt = 0; jt < 8; ++jt)
                brg[rr][jt] = bb[(size_t)rr * SEQ + jt * 16];
    }

    // ---- phase 1: QK^T via MFMA, scores stay in registers
    f32x4 sc[8];
    {
        const __bf16* __restrict__ Qp = Qb + ((size_t)bh * SEQ + s0) * DH;
        const __bf16* __restrict__ Kp = Kb + ((size_t)bh * SEQ + wave * 128) * DH;
        const bf16x8 qa0 = *(const bf16x8*)(Qp + r * DH + kc * 8);
        const bf16x8 qa1 = *(const bf16x8*)(Qp + r * DH + 32 + kc * 8);
        __builtin_amdgcn_s_setprio(1);
        #pragma unroll
        for (int jt = 0; jt < 8; ++jt) {
            const bf16x8 kb0 = *(const bf16x8*)(Kp + (size_t)(jt * 16 + r) * DH + kc * 8);
            const bf16x8 kb1 = *(const bf16x8*)(Kp + (size_t)(jt * 16 + r) * DH + 32 + kc * 8);
            f32x4 a = {0.f, 0.f, 0.f, 0.f};
            a = __builtin_amdgcn_mfma_f32_16x16x32_bf16(qa0, kb0, a, 0, 0, 0);
            a = __builtin_amdgcn_mfma_f32_16x16x32_bf16(qa1, kb1, a, 0, 0, 0);
            sc[jt] = a;
        }
        __builtin_amdgcn_s_setprio(0);
    }

    // ---- phase 1.5: bias add + exp (no-max) + per-row partial sums
    float psum[4] = {0.f, 0.f, 0.f, 0.f};
    #pragma unroll
    for (int jt = 0; jt < 8; ++jt) {
        #pragma unroll
        for (int rr = 0; rr < 4; ++rr) {
            const float s = fmaf(sc[jt][rr], 0.125f,
                                 __uint_as_float(brg[rr][jt] << 16));
            const float p = __expf(fminf(s, 30.f));
            sc[jt][rr] = p;
            psum[rr] += p;
        }
    }
    // reduce across the 16 lanes (r) of each kc group
    #pragma unroll
    for (int mask = 8; mask >= 1; mask >>= 1)
        #pragma unroll
        for (int rr = 0; rr < 4; ++rr)
            psum[rr] += __shfl_xor(psum[rr], mask);
    if (r == 0) {
        #pragma unroll
        for (int rr = 0; rr < 4; ++rr) red[wave][kc * 4 + rr] = psum[rr];
    }
    // write un-normalized P (bf16) to LDS
    #pragma unroll
    for (int jt = 0; jt < 8; ++jt)
        #pragma unroll
        for (int rr = 0; rr < 4; ++rr)
            Pb[(kc * 4 + rr) * PSTR + wave * 128 + jt * 16 + r] = (__bf16)sc[jt][rr];
    __syncthreads();

    if (t < 16) {
        float l = 0.f;
        #pragma unroll
        for (int w = 0; w < 8; ++w) l += red[w][t];
        invl[t] = 1.0f / l;
    }

    // ---- phase 3: P @ V ; wave = (c-tile = wave&3, K-half = wave>>2)
    {
        const int ct = wave & 3, kh = wave >> 2;
        const __bf16* __restrict__ Vp =
            Vtb + ((size_t)bh * DH + ct * 16 + r) * SEQ + kh * 512;
        f32x4 acc = {0.f, 0.f, 0.f, 0.f};
        __builtin_amdgcn_s_setprio(1);
        #pragma unroll 4
        for (int jt = 0; jt < 16; ++jt) {
            const bf16x8 pa = *(const bf16x8*)&Pb[r * PSTR + kh * 512 + jt * 32 + kc * 8];
            const bf16x8 vb = *(const bf16x8*)(Vp + jt * 32 + kc * 8);
            acc = __builtin_amdgcn_mfma_f32_16x16x32_bf16(pa, vb, acc, 0, 0, 0);
        }
        __builtin_amdgcn_s_setprio(0);
        if (kh == 1) {
            #pragma unroll
            for (int rr = 0; rr < 4; ++rr)
                part[ct * 272 + (kc * 4 + rr) * 17 + r] = acc[rr];
        }
        __syncthreads();
        if (kh == 0) {
            #pragma unroll
            for (int rr = 0; rr < 4; ++rr) {
                const int row = kc * 4 + rr;
                const float v = (acc[rr] + part[ct * 272 + row * 17 + r]) * invl[row];
                ctxb[((size_t)(b * SEQ) + s0 + row) * DM + h * DH + ct * 16 + r] = (__bf16)v;
            }
        }
    }
}

// ---------------------------------------------------------------------------
// MFMA GEMM (out). XCD-swizzled grid (128 blocks).
// ---------------------------------------------------------------------------
__global__ __launch_bounds__(256) void gemm_out_mfma(
    const __bf16* __restrict__ ctxb, const __bf16* __restrict__ Wot,
    const float* __restrict__ bo, float* __restrict__ out)
{
    const int t = threadIdx.x;
    const int wave = t >> 6, lane = t & 63;
    const int wm = wave >> 1, wn = wave & 1;
    const int r = lane & 15, kc = lane >> 4, q4 = kc * 4;
    const int lin = blockIdx.y * 4 + blockIdx.x;             // 0..127
    const int swz = (lin & 7) * 16 + (lin >> 3);
    const int m0 = (swz / 4) * 128;
    const int n0 = (swz % 4) * 128;

    __shared__ __align__(16) char smem[36864];
    __bf16* __restrict__ As = (__bf16*)smem;
    __bf16* __restrict__ Bs = (__bf16*)(smem + 18432);

    f32x4 acc[4][4];
    #pragma unroll
    for (int i = 0; i < 4; ++i)
        #pragma unroll
        for (int j = 0; j < 4; ++j) acc[i][j] = {0.f, 0.f, 0.f, 0.f};

    const int srow = t >> 3, sck = (t & 7) * 8;
    const __bf16* __restrict__ Ag = ctxb + (size_t)(m0 + srow) * 512 + sck;
    const __bf16* __restrict__ Bg = Wot + (size_t)(n0 + srow) * 512 + sck;

    for (int k0 = 0; k0 < 512; k0 += 64) {
        bf16x8 ra[4], rb[4];
        #pragma unroll
        for (int i = 0; i < 4; ++i) {
            ra[i] = *(const bf16x8*)(Ag + (size_t)i * 32 * 512 + k0);
            rb[i] = *(const bf16x8*)(Bg + (size_t)i * 32 * 512 + k0);
        }
        __syncthreads();
        #pragma unroll
        for (int i = 0; i < 4; ++i) {
            *(bf16x8*)&As[(srow + i * 32) * 72 + sck] = ra[i];
            *(bf16x8*)&Bs[(srow + i * 32) * 72 + sck] = rb[i];
        }
        __syncthreads();
        #pragma unroll
        for (int ks = 0; ks < 2; ++ks) {
            bf16x8 af[4], bf[4];
            #pragma unroll
            for (int mf = 0; mf < 4; ++mf)
                af[mf] = *(const bf16x8*)&As[(wm * 64 + mf * 16 + r) * 72 + ks * 32 + kc * 8];
            #pragma unroll
            for (int nf = 0; nf < 4; ++nf)
                bf[nf] = *(const bf16x8*)&Bs[(wn * 64 + nf * 16 + r) * 72 + ks * 32 + kc * 8];
            #pragma unroll
            for (int mf = 0; mf < 4; ++mf)
                #pragma unroll
                for (int nf = 0; nf < 4; ++nf)
                    acc[mf][nf] = __builtin_amdgcn_mfma_f32_16x16x32_bf16(
                        af[mf], bf[nf], acc[mf][nf], 0, 0, 0);
        }
    }

    #pragma unroll
    for (int mf = 0; mf < 4; ++mf)
        #pragma unroll
        for (int nf = 0; nf < 4; ++nf) {
            const int n_l = wn * 64 + nf * 16 + r;
            const float bb = bo[n0 + n_l];
            #pragma unroll
            for (int rr = 0; rr < 4; ++rr)
                out[(size_t)(m0 + wm * 64 + mf * 16 + q4 + rr) * DM + n0 + n_l] =
                    acc[mf][nf][rr] + bb;
        }
}

// ---------------------------------------------------------------------------
extern "C" void kernel_launch(void* const* d_in, const int* in_sizes, int n_in,
                              void* d_out, int out_size, void* d_ws, size_t ws_size,
                              hipStream_t stream)
{
    const float* x     = (const float*)d_in[0];
    const float* freqs = (const float*)d_in[1];
    const float* Wq    = (const float*)d_in[2];
    const float* bq    = (const float*)d_in[3];
    const float* Wk    = (const float*)d_in[4];
    const float* bk    = (const float*)d_in[5];
    const float* Wv    = (const float*)d_in[6];
    const float* bv    = (const float*)d_in[7];
    const float* Wo    = (const float*)d_in[8];
    const float* bo    = (const float*)d_in[9];
    const float* W1    = (const float*)d_in[10];
    const float* b1    = (const float*)d_in[11];
    const float* W2    = (const float*)d_in[12];
    // b2 (d_in[13]) is softmax-invariant: dropped.

    char* wsb = (char*)d_ws;
    __bf16* Qb    = (__bf16*)(wsb + QB_OFF);
    __bf16* Kb    = (__bf16*)(wsb + KB_OFF);
    __bf16* Vtb   = (__bf16*)(wsb + VT_OFF);
    __bf16* xb    = (__bf16*)(wsb + XB_OFF);
    __bf16* Wt    = (__bf16*)(wsb + WT_OFF);
    __bf16* Wot   = (__bf16*)(wsb + WOT_OFF);
    __bf16* W2t   = (__bf16*)(wsb + W2T_OFF);
    float*  Aw    = (float*)(wsb + AW_OFF);
    float*  Cw    = (float*)(wsb + CW_OFF);
    __bf16* ctxb  = (__bf16*)(wsb + CTXB_OFF);
    __bf16* biasb = (__bf16*)(wsb + BIAS_OFF);
    float* out = (float*)d_out;

    prologue<<<dim3(2304), 256, 0, stream>>>(
        x, Wq, Wk, Wv, Wo, freqs, W1, b1, W2, xb, Wt, Wot, Aw, Cw, W2t);
    mid_fused<<<dim3(1408), 256, 0, stream>>>(
        xb, Wt, bq, bk, bv, Qb, Kb, Vtb, Aw, Cw, W2t, biasb);
    attn_mfma<<<dim3(2048), 512, 0, stream>>>(Qb, Kb, Vtb, biasb, ctxb);
    gemm_out_mfma<<<dim3(4, 32), 256, 0, stream>>>(ctxb, Wot, bo, out);
}